// Round 4
// baseline (244.803 us; speedup 1.0000x reference)
//
#include <hip/hip_runtime.h>
#include <math.h>

#define INC   128
#define OUTC  256
#define NPTS  9
#define BATCH 8
#define HDIM  64
#define WDIM  64
#define HW    4096          // 64*64
#define JLB   36864         // cols per batch = 64*64*9
#define JTOT  294912        // 8 * JLB
#define NTOTF 294912.0f

typedef __bf16 bf16x8 __attribute__((ext_vector_type(8)));
typedef float  f32x4  __attribute__((ext_vector_type(4)));

__device__ __forceinline__ void load_lds16(const void* g, void* lds) {
    __builtin_amdgcn_global_load_lds(
        (const __attribute__((address_space(1))) unsigned int*)g,
        (__attribute__((address_space(3))) unsigned int*)lds, 16, 0, 0);
}

// ---------------- K0: cw fp32 -> bf16 ----------------
__global__ void k_cvt_cw(const float* __restrict__ cw, __bf16* __restrict__ cwb) {
    int i = blockIdx.x * 256 + threadIdx.x;
    if (i < OUTC * INC) cwb[i] = (__bf16)cw[i];
}

// ---------------- K0b: transpose x (b,c,hw) f32 -> xTb (b,hw,c) bf16 -------
__global__ __launch_bounds__(256) void k_transpose(
        const float* __restrict__ x, __bf16* __restrict__ xTb) {
    __shared__ __bf16 t[64 * 128];
    char* tb = (char*)t;
    int b   = blockIdx.x >> 6;
    int hw0 = (blockIdx.x & 63) << 6;
    int tid = threadIdx.x;
    int lane = tid & 63;
    int cq  = tid >> 6;
    const float* xb = x + b * (INC * HW);
    #pragma unroll
    for (int cc = 0; cc < INC; cc += 4) {
        int c = cc + cq;
        float v = xb[c * HW + hw0 + lane];
        *(__bf16*)(tb + lane * 256 + ((2 * c) ^ ((lane & 15) << 4))) = (__bf16)v;
    }
    __syncthreads();
    __bf16* ob = xTb + ((size_t)b * HW + hw0) * INC;
    #pragma unroll
    for (int i = 0; i < 4; ++i) {
        int chunk = i * 256 + tid;
        int hw  = chunk >> 4;
        int c16 = chunk & 15;
        bf16x8 vv = *(bf16x8*)(tb + hw * 256 + ((c16 * 16) ^ ((hw & 15) << 4)));
        *(bf16x8*)(ob + hw * INC + c16 * 8) = vv;
    }
}

// ---------------- K1: offset conv + sampling prep (round-2 validated) ------
__global__ __launch_bounds__(256) void k_prep(
        const float* __restrict__ x, const float* __restrict__ pw,
        const float* __restrict__ pb, int4* __restrict__ sidx,
        float4* __restrict__ sw) {
    int n  = blockIdx.x >> 7;                         // 0..8
    int sp = ((blockIdx.x & 127) << 8) + threadIdx.x; // 0..32767
    int b  = sp >> 12;
    int hh = (sp >> 6) & 63;
    int ww = sp & 63;

    __shared__ float pwl[INC * 9 * 2];
    for (int i = threadIdx.x; i < INC * 9; i += 256) {
        pwl[i * 2 + 0] = pw[n * (INC * 9) + i];
        pwl[i * 2 + 1] = pw[(n + 9) * (INC * 9) + i];
    }
    __syncthreads();

    const float* xb = x + b * (INC * HW);
    float ax = 0.f, ay = 0.f;
    for (int c = 0; c < INC; ++c) {
        const float* xc = xb + c * HW;
        const float* pc = pwl + c * 18;
        #pragma unroll
        for (int ky = 0; ky < 3; ++ky) {
            int yy = hh - 1 + ky;
            #pragma unroll
            for (int kx = 0; kx < 3; ++kx) {
                int xx = ww - 1 + kx;
                float v = ((unsigned)yy < 64u && (unsigned)xx < 64u)
                            ? xc[yy * 64 + xx] : 0.f;
                int k = ky * 3 + kx;
                ax = fmaf(v, pc[k * 2 + 0], ax);
                ay = fmaf(v, pc[k * 2 + 1], ay);
            }
        }
    }
    ax += pb[n];
    ay += pb[n + 9];

    const float TWO_PI = 6.28318530717958647692f;
    float ang = (float)n * (TWO_PI / 9.0f);
    float px = ax + cosf(ang) + (float)hh;
    float py = ay + sinf(ang) + (float)ww;
    float fx = floorf(px), fy = floorf(py);
    float ltx = fminf(fmaxf(fx,        0.f), 63.f);
    float lty = fminf(fmaxf(fy,        0.f), 63.f);
    float rbx = fminf(fmaxf(fx + 1.f,  0.f), 63.f);
    float rby = fminf(fmaxf(fy + 1.f,  0.f), 63.f);
    float pxc = fminf(fmaxf(px,        0.f), 63.f);
    float pyc = fminf(fmaxf(py,        0.f), 63.f);
    float glt = (1.f + ltx - pxc) * (1.f + lty - pyc);
    float grb = (1.f - rbx + pxc) * (1.f - rby + pyc);
    float glb = (1.f + ltx - pxc) * (1.f - rby + pyc);
    float grt = (1.f - rbx + pxc) * (1.f + lty - pyc);

    int j = b * JLB + (hh * 64 + ww) * 9 + n;
    sidx[j] = make_int4((int)ltx * 64 + (int)lty,
                        (int)rbx * 64 + (int)rby,
                        (int)ltx * 64 + (int)rby,
                        (int)rbx * 64 + (int)lty);
    sw[j] = make_float4(glt, grb, glb, grt);
}

// ---------------- K2: gather-GEMM (round-2 validated orientation) ----------
// WRITE=false: stats pass (optionally dumping swizzled xoff tile to global).
// WRITE=true : fallback output pass (round-2 exact).
template <bool WRITE, bool XOFF>
__global__ __launch_bounds__(256, 2) void k_gemm(
        const __bf16* __restrict__ xTb, const __bf16* __restrict__ cwb,
        const int4* __restrict__ sidx, const float4* __restrict__ sw,
        const float* __restrict__ scaleb, const float* __restrict__ shiftb,
        float* __restrict__ gstat, float* __restrict__ out,
        __bf16* __restrict__ xoffG) {
    __shared__ uint4 xoffT4[64 * 256 / 16];   // 64 j x 128 c bf16, swizzled
    __shared__ float saux[512];
    char* xoffT = (char*)xoffT4;

    int bidx = blockIdx.x;
    int b    = bidx / 576;
    int jl0  = (bidx % 576) * 64;
    int tid  = threadIdx.x;
    int w    = tid >> 6;
    int l    = tid & 63;

    // ---- gather + bilinear interp: thread = (column j, channel-quarter)
    int col = tid >> 2;                 // 0..63
    int q   = tid & 3;                  // channels [32q, 32q+32)
    int j   = b * JLB + jl0 + col;
    int4   qi = sidx[j];
    float4 qw = sw[j];
    const __bf16* xtb = xTb + (size_t)b * (HW * INC) + q * 32;

    float accc[32];
    #pragma unroll
    for (int i = 0; i < 32; ++i) accc[i] = 0.f;

    const int   idx4[4] = { qi.x, qi.y, qi.z, qi.w };
    const float wt4[4]  = { qw.x, qw.y, qw.z, qw.w };
    #pragma unroll
    for (int p = 0; p < 4; ++p) {
        const __bf16* rp = xtb + idx4[p] * INC;
        float wp = wt4[p];
        #pragma unroll
        for (int v = 0; v < 4; ++v) {
            bf16x8 vv = *(const bf16x8*)(rp + v * 8);
            #pragma unroll
            for (int i = 0; i < 8; ++i)
                accc[v * 8 + i] = fmaf(wp, (float)vv[i], accc[v * 8 + i]);
        }
    }
    char* xg = XOFF ? ((char*)xoffG + (size_t)bidx * 16384) : nullptr;
    #pragma unroll
    for (int i8 = 0; i8 < 4; ++i8) {
        bf16x8 pk;
        #pragma unroll
        for (int i = 0; i < 8; ++i) pk[i] = (__bf16)accc[i8 * 8 + i];
        int colbyte = (q * 64 + i8 * 16) ^ ((col & 7) << 4);   // XOR swizzle
        *(bf16x8*)(xoffT + col * 256 + colbyte) = pk;
        if (XOFF)
            *(bf16x8*)(xg + col * 256 + colbyte) = pk;         // same byte image
    }

    if (WRITE) {
        saux[tid]       = scaleb[tid];
        saux[256 + tid] = shiftb[tid];
    }

    // ---- A fragments (cw rows for this wave), L2-hot
    bf16x8 afrag[4][4];   // [mtile][kstep]
    #pragma unroll
    for (int mt = 0; mt < 4; ++mt) {
        int m = w * 64 + mt * 16 + (l & 15);
        #pragma unroll
        for (int ks = 0; ks < 4; ++ks) {
            int k = ks * 32 + (l >> 4) * 8;
            afrag[mt][ks] = *(const bf16x8*)(cwb + m * 128 + k);
        }
    }

    __syncthreads();

    // ---- MFMA: acc[mt][nt], A = cw (o rows), B = xoff (j cols)
    f32x4 acc[4][4] = {};
    #pragma unroll
    for (int ks = 0; ks < 4; ++ks) {
        bf16x8 bfrag[4];
        #pragma unroll
        for (int nt = 0; nt < 4; ++nt) {
            int row = nt * 16 + (l & 15);
            int colbyte = (ks * 64 + (l >> 4) * 16) ^ ((row & 7) << 4);
            bfrag[nt] = *(const bf16x8*)(xoffT + row * 256 + colbyte);
        }
        #pragma unroll
        for (int mt = 0; mt < 4; ++mt)
            #pragma unroll
            for (int nt = 0; nt < 4; ++nt)
                acc[mt][nt] = __builtin_amdgcn_mfma_f32_16x16x32_bf16(
                    afrag[mt][ks], bfrag[nt], acc[mt][nt], 0, 0, 0);
    }

    if (WRITE) {
        float* outb = out + (size_t)b * (OUTC * JLB);
        #pragma unroll
        for (int mt = 0; mt < 4; ++mt) {
            #pragma unroll
            for (int r = 0; r < 4; ++r) {
                int o = w * 64 + mt * 16 + (l >> 4) * 4 + r;
                float sc = saux[o];
                float sh = saux[256 + o];
                float* orow = outb + (size_t)o * JLB + jl0 + (l & 15);
                #pragma unroll
                for (int nt = 0; nt < 4; ++nt) {
                    float yn = fmaf(acc[mt][nt][r], sc, sh);
                    float so = yn / (1.f + __expf(-yn));
                    orow[nt * 16] = so;
                }
            }
        }
    } else {
        float* ssum = saux;
        float* ssq  = saux + 256;
        #pragma unroll
        for (int mt = 0; mt < 4; ++mt) {
            #pragma unroll
            for (int r = 0; r < 4; ++r) {
                float s = 0.f, qq = 0.f;
                #pragma unroll
                for (int nt = 0; nt < 4; ++nt) {
                    float v = acc[mt][nt][r];
                    s  += v;
                    qq += v * v;
                }
                #pragma unroll
                for (int d = 1; d < 16; d <<= 1) {
                    s  += __shfl_xor(s, d, 64);
                    qq += __shfl_xor(qq, d, 64);
                }
                if ((l & 15) == 0) {
                    int row = w * 64 + mt * 16 + (l >> 4) * 4 + r;
                    ssum[row] = s;
                    ssq[row]  = qq;
                }
            }
        }
        __syncthreads();
        float* gs = gstat + (bidx & 63) * 512;   // 64-way replicated
        atomicAdd(gs + tid,       ssum[tid]);
        atomicAdd(gs + 256 + tid, ssq[tid]);
    }
}

// ---------------- K2b: output pass from stored xoff tiles ----------------
// Stages the pre-swizzled 16 KB tile linearly via global_load_lds, then the
// round-2-validated LDS reader / MFMA / epilogue.
__global__ __launch_bounds__(256, 2) void k_out(
        const __bf16* __restrict__ xoffG, const __bf16* __restrict__ cwb,
        const float* __restrict__ scaleb, const float* __restrict__ shiftb,
        float* __restrict__ out) {
    __shared__ uint4 xoffT4[64 * 256 / 16];   // 16 KB
    __shared__ float saux[512];
    char* xoffT = (char*)xoffT4;

    int bidx = blockIdx.x;
    int b    = bidx / 576;
    int jl0  = (bidx % 576) * 64;
    int tid  = threadIdx.x;
    int w    = tid >> 6;
    int l    = tid & 63;

    // ---- stage 16 KB tile: per wave 4 KB = 4 x (64 lanes x 16 B)
    const char* gsrc = (const char*)xoffG + (size_t)bidx * 16384 + w * 4096;
    char*       ldst = xoffT + w * 4096;
    #pragma unroll
    for (int it = 0; it < 4; ++it)
        load_lds16(gsrc + it * 1024 + l * 16, ldst + it * 1024);

    saux[tid]       = scaleb[tid];
    saux[256 + tid] = shiftb[tid];

    bf16x8 afrag[4][4];
    #pragma unroll
    for (int mt = 0; mt < 4; ++mt) {
        int m = w * 64 + mt * 16 + (l & 15);
        #pragma unroll
        for (int ks = 0; ks < 4; ++ks) {
            int k = ks * 32 + (l >> 4) * 8;
            afrag[mt][ks] = *(const bf16x8*)(cwb + m * 128 + k);
        }
    }

    __syncthreads();

    f32x4 acc[4][4] = {};
    #pragma unroll
    for (int ks = 0; ks < 4; ++ks) {
        bf16x8 bfrag[4];
        #pragma unroll
        for (int nt = 0; nt < 4; ++nt) {
            int row = nt * 16 + (l & 15);
            int colbyte = (ks * 64 + (l >> 4) * 16) ^ ((row & 7) << 4);
            bfrag[nt] = *(const bf16x8*)(xoffT + row * 256 + colbyte);
        }
        #pragma unroll
        for (int mt = 0; mt < 4; ++mt)
            #pragma unroll
            for (int nt = 0; nt < 4; ++nt)
                acc[mt][nt] = __builtin_amdgcn_mfma_f32_16x16x32_bf16(
                    afrag[mt][ks], bfrag[nt], acc[mt][nt], 0, 0, 0);
    }

    float* outb = out + (size_t)b * (OUTC * JLB);
    #pragma unroll
    for (int mt = 0; mt < 4; ++mt) {
        #pragma unroll
        for (int r = 0; r < 4; ++r) {
            int o = w * 64 + mt * 16 + (l >> 4) * 4 + r;
            float sc = saux[o];
            float sh = saux[256 + o];
            float* orow = outb + (size_t)o * JLB + jl0 + (l & 15);
            #pragma unroll
            for (int nt = 0; nt < 4; ++nt) {
                float yn = fmaf(acc[mt][nt][r], sc, sh);
                float so = yn / (1.f + __expf(-yn));
                orow[nt * 16] = so;
            }
        }
    }
}

// ---------------- K3: reduce stats -> scale, shift ----------------
__global__ void k_stats(const float* __restrict__ gstat,
                        const float* __restrict__ gamma,
                        const float* __restrict__ beta,
                        float* __restrict__ scaleb, float* __restrict__ shiftb) {
    int t = threadIdx.x;
    float s = 0.f, q = 0.f;
    for (int r = 0; r < 64; ++r) {
        s += gstat[r * 512 + t];
        q += gstat[r * 512 + 256 + t];
    }
    float mean = s / NTOTF;
    float var  = q / NTOTF - mean * mean;
    float rstd = rsqrtf(var + 1e-5f);
    float sc = rstd * gamma[t];
    scaleb[t] = sc;
    shiftb[t] = beta[t] - mean * sc;
}

// ---------------- host ----------------
extern "C" void kernel_launch(void* const* d_in, const int* in_sizes, int n_in,
                              void* d_out, int out_size, void* d_ws, size_t ws_size,
                              hipStream_t stream) {
    (void)in_sizes; (void)n_in; (void)out_size;
    const float* x     = (const float*)d_in[0];
    const float* pw    = (const float*)d_in[1];
    const float* pb    = (const float*)d_in[2];
    const float* cw    = (const float*)d_in[3];
    const float* gamma = (const float*)d_in[4];
    const float* beta  = (const float*)d_in[5];
    float* out = (float*)d_out;

    char* ws = (char*)d_ws;
    const size_t XOFF_BYTES = (size_t)4608 * 16384;        // 75,497,472
    bool big = ws_size >= (XOFF_BYTES + 18087936ull);      // + small-path needs

    size_t off = big ? XOFF_BYTES : 0;
    __bf16* xoffG = (__bf16*)ws;                           // big path only
    __bf16* xTb   = (__bf16*)(ws + off);                   // 8,388,608
    int4*   sidx  = (int4*)(ws + off + 8388608);           // 4,718,592
    float4* swt   = (float4*)(ws + off + 13107200);        // 4,718,592
    __bf16* cwb   = (__bf16*)(ws + off + 17825792);        // 65,536
    float*  gstat = (float*)(ws + off + 17891328);         // 131,072
    float*  scaleb= (float*)(ws + off + 18022400);         // 1,024
    float*  shiftb= (float*)(ws + off + 18023424);         // 1,024 -> +18,087,936? (rounded up in guard)

    hipMemsetAsync(gstat, 0, 64 * 512 * 4, stream);
    k_cvt_cw<<<128, 256, 0, stream>>>(cw, cwb);
    k_transpose<<<512, 256, 0, stream>>>(x, xTb);
    k_prep<<<9 * 128, 256, 0, stream>>>(x, pw, pb, sidx, swt);
    if (big) {
        k_gemm<false, true><<<4608, 256, 0, stream>>>(
            xTb, cwb, sidx, swt, nullptr, nullptr, gstat, nullptr, xoffG);
        k_stats<<<1, 256, 0, stream>>>(gstat, gamma, beta, scaleb, shiftb);
        k_out<<<4608, 256, 0, stream>>>(xoffG, cwb, scaleb, shiftb, out);
    } else {
        k_gemm<false, false><<<4608, 256, 0, stream>>>(
            xTb, cwb, sidx, swt, nullptr, nullptr, gstat, nullptr, nullptr);
        k_stats<<<1, 256, 0, stream>>>(gstat, gamma, beta, scaleb, shiftb);
        k_gemm<true, false><<<4608, 256, 0, stream>>>(
            xTb, cwb, sidx, swt, scaleb, shiftb, gstat, out, nullptr);
    }
}

// Round 5
// 227.058 us; speedup vs baseline: 1.0782x; 1.0782x over previous
//
#include <hip/hip_runtime.h>
#include <math.h>

#define INC   128
#define OUTC  256
#define NPTS  9
#define BATCH 8
#define HDIM  64
#define WDIM  64
#define HW    4096          // 64*64
#define JLB   36864         // cols per batch = 64*64*9
#define JTOT  294912        // 8 * JLB
#define NTOTF 294912.0f

typedef __bf16 bf16x8 __attribute__((ext_vector_type(8)));
typedef float  f32x4  __attribute__((ext_vector_type(4)));

// ---------------- K0: cw fp32 -> bf16 ----------------
__global__ void k_cvt_cw(const float* __restrict__ cw, __bf16* __restrict__ cwb) {
    int i = blockIdx.x * 256 + threadIdx.x;
    if (i < OUTC * INC) cwb[i] = (__bf16)cw[i];
}

// ---------------- K0b: transpose x (b,c,hw) f32 -> xTb (b,hw,c) bf16 -------
__global__ __launch_bounds__(256) void k_transpose(
        const float* __restrict__ x, __bf16* __restrict__ xTb) {
    __shared__ __bf16 t[64 * 128];
    char* tb = (char*)t;
    int b   = blockIdx.x >> 6;
    int hw0 = (blockIdx.x & 63) << 6;
    int tid = threadIdx.x;
    int lane = tid & 63;
    int cq  = tid >> 6;
    const float* xb = x + b * (INC * HW);
    #pragma unroll
    for (int cc = 0; cc < INC; cc += 4) {
        int c = cc + cq;
        float v = xb[c * HW + hw0 + lane];
        *(__bf16*)(tb + lane * 256 + ((2 * c) ^ ((lane & 15) << 4))) = (__bf16)v;
    }
    __syncthreads();
    __bf16* ob = xTb + ((size_t)b * HW + hw0) * INC;
    #pragma unroll
    for (int i = 0; i < 4; ++i) {
        int chunk = i * 256 + tid;
        int hw  = chunk >> 4;
        int c16 = chunk & 15;
        bf16x8 vv = *(bf16x8*)(tb + hw * 256 + ((c16 * 16) ^ ((hw & 15) << 4)));
        *(bf16x8*)(ob + hw * INC + c16 * 8) = vv;
    }
}

// ---------------- K1: offset conv + sampling prep (f32 — MUST stay f32:
// reference sampling is discontinuous in px/py at clip boundaries; offset
// perturbation flips branches -> O(1) output error) ----------------
__global__ __launch_bounds__(256) void k_prep(
        const float* __restrict__ x, const float* __restrict__ pw,
        const float* __restrict__ pb, int4* __restrict__ sidx,
        float4* __restrict__ sw) {
    int n  = blockIdx.x >> 7;                         // 0..8
    int sp = ((blockIdx.x & 127) << 8) + threadIdx.x; // 0..32767
    int b  = sp >> 12;
    int hh = (sp >> 6) & 63;
    int ww = sp & 63;

    __shared__ float pwl[INC * 9 * 2];
    for (int i = threadIdx.x; i < INC * 9; i += 256) {
        pwl[i * 2 + 0] = pw[n * (INC * 9) + i];
        pwl[i * 2 + 1] = pw[(n + 9) * (INC * 9) + i];
    }
    __syncthreads();

    const float* xb = x + b * (INC * HW);
    float ax = 0.f, ay = 0.f;
    for (int c = 0; c < INC; ++c) {
        const float* xc = xb + c * HW;
        const float* pc = pwl + c * 18;
        #pragma unroll
        for (int ky = 0; ky < 3; ++ky) {
            int yy = hh - 1 + ky;
            #pragma unroll
            for (int kx = 0; kx < 3; ++kx) {
                int xx = ww - 1 + kx;
                float v = ((unsigned)yy < 64u && (unsigned)xx < 64u)
                            ? xc[yy * 64 + xx] : 0.f;
                int k = ky * 3 + kx;
                ax = fmaf(v, pc[k * 2 + 0], ax);
                ay = fmaf(v, pc[k * 2 + 1], ay);
            }
        }
    }
    ax += pb[n];
    ay += pb[n + 9];

    const float TWO_PI = 6.28318530717958647692f;
    float ang = (float)n * (TWO_PI / 9.0f);
    float px = ax + cosf(ang) + (float)hh;
    float py = ay + sinf(ang) + (float)ww;
    float fx = floorf(px), fy = floorf(py);
    float ltx = fminf(fmaxf(fx,        0.f), 63.f);
    float lty = fminf(fmaxf(fy,        0.f), 63.f);
    float rbx = fminf(fmaxf(fx + 1.f,  0.f), 63.f);
    float rby = fminf(fmaxf(fy + 1.f,  0.f), 63.f);
    float pxc = fminf(fmaxf(px,        0.f), 63.f);
    float pyc = fminf(fmaxf(py,        0.f), 63.f);
    float glt = (1.f + ltx - pxc) * (1.f + lty - pyc);
    float grb = (1.f - rbx + pxc) * (1.f - rby + pyc);
    float glb = (1.f + ltx - pxc) * (1.f - rby + pyc);
    float grt = (1.f - rbx + pxc) * (1.f + lty - pyc);

    int j = b * JLB + (hh * 64 + ww) * 9 + n;
    sidx[j] = make_int4((int)ltx * 64 + (int)lty,
                        (int)rbx * 64 + (int)rby,
                        (int)ltx * 64 + (int)rby,
                        (int)rbx * 64 + (int)lty);
    sw[j] = make_float4(glt, grb, glb, grt);
}

// ---------------- K2: gather-GEMM ----------------
// WRITE=false (stats): validated round-2 orientation. A=cw(row=o), B=xoff(col=j).
// WRITE=true  (output): swapped orientation. A=xoff(row=j), B=cw(col=o) so
//   D row=j=(l>>4)*4+r -> f32x4 stores along j (16 dwordx4/thread vs 64 dword).
template <bool WRITE>
__global__ __launch_bounds__(256, 2) void k_gemm(
        const __bf16* __restrict__ xTb, const __bf16* __restrict__ cwb,
        const int4* __restrict__ sidx, const float4* __restrict__ sw,
        const float* __restrict__ scaleb, const float* __restrict__ shiftb,
        float* __restrict__ gstat, float* __restrict__ out) {
    __shared__ uint4 xoffT4[64 * 256 / 16];   // 64 j x 128 c bf16, swizzled
    __shared__ float saux[512];
    char* xoffT = (char*)xoffT4;

    int bidx = blockIdx.x;
    int b    = bidx / 576;
    int jl0  = (bidx % 576) * 64;
    int tid  = threadIdx.x;
    int w    = tid >> 6;
    int l    = tid & 63;

    // ---- gather + bilinear interp: thread = (column j, channel-quarter)
    int col = tid >> 2;                 // 0..63
    int q   = tid & 3;                  // channels [32q, 32q+32)
    int j   = b * JLB + jl0 + col;
    int4   qi = sidx[j];
    float4 qw = sw[j];
    const __bf16* xtb = xTb + (size_t)b * (HW * INC) + q * 32;

    float accc[32];
    #pragma unroll
    for (int i = 0; i < 32; ++i) accc[i] = 0.f;

    const int   idx4[4] = { qi.x, qi.y, qi.z, qi.w };
    const float wt4[4]  = { qw.x, qw.y, qw.z, qw.w };
    #pragma unroll
    for (int p = 0; p < 4; ++p) {
        const __bf16* rp = xtb + idx4[p] * INC;
        float wp = wt4[p];
        #pragma unroll
        for (int v = 0; v < 4; ++v) {
            bf16x8 vv = *(const bf16x8*)(rp + v * 8);
            #pragma unroll
            for (int i = 0; i < 8; ++i)
                accc[v * 8 + i] = fmaf(wp, (float)vv[i], accc[v * 8 + i]);
        }
    }
    #pragma unroll
    for (int i8 = 0; i8 < 4; ++i8) {
        bf16x8 pk;
        #pragma unroll
        for (int i = 0; i < 8; ++i) pk[i] = (__bf16)accc[i8 * 8 + i];
        int colbyte = (q * 64 + i8 * 16) ^ ((col & 7) << 4);   // XOR swizzle
        *(bf16x8*)(xoffT + col * 256 + colbyte) = pk;
    }

    if (WRITE) {
        saux[tid]       = scaleb[tid];
        saux[256 + tid] = shiftb[tid];
    }

    if (WRITE) {
        // ---- B fragments: cw columns o for this wave (L2-hot)
        bf16x8 bfrag[4][4];   // [ot][ks]
        #pragma unroll
        for (int ot = 0; ot < 4; ++ot) {
            int o = w * 64 + ot * 16 + (l & 15);
            #pragma unroll
            for (int ks = 0; ks < 4; ++ks) {
                int k = ks * 32 + (l >> 4) * 8;
                bfrag[ot][ks] = *(const bf16x8*)(cwb + o * 128 + k);
            }
        }
        __syncthreads();

        // ---- MFMA: acc[jt][ot], A = xoff (row=j), B = cw (col=o)
        f32x4 acc[4][4] = {};
        #pragma unroll
        for (int ks = 0; ks < 4; ++ks) {
            bf16x8 afrag[4];
            #pragma unroll
            for (int jt = 0; jt < 4; ++jt) {
                int row = jt * 16 + (l & 15);
                int colbyte = (ks * 64 + (l >> 4) * 16) ^ ((row & 7) << 4);
                afrag[jt] = *(const bf16x8*)(xoffT + row * 256 + colbyte);
            }
            #pragma unroll
            for (int jt = 0; jt < 4; ++jt)
                #pragma unroll
                for (int ot = 0; ot < 4; ++ot)
                    acc[jt][ot] = __builtin_amdgcn_mfma_f32_16x16x32_bf16(
                        afrag[jt], bfrag[ot][ks], acc[jt][ot], 0, 0, 0);
        }

        float* outb = out + (size_t)b * (OUTC * JLB);
        #pragma unroll
        for (int ot = 0; ot < 4; ++ot) {
            int o = w * 64 + ot * 16 + (l & 15);
            float sc = saux[o];
            float sh = saux[256 + o];
            float* orow = outb + (size_t)o * JLB + jl0 + (l >> 4) * 4;
            #pragma unroll
            for (int jt = 0; jt < 4; ++jt) {
                f32x4 vst;
                #pragma unroll
                for (int r = 0; r < 4; ++r) {
                    float yn = fmaf(acc[jt][ot][r], sc, sh);
                    vst[r] = yn / (1.f + __expf(-yn));
                }
                *(f32x4*)(orow + jt * 16) = vst;
            }
        }
    } else {
        // ---- A fragments (cw rows for this wave), validated orientation
        bf16x8 afrag[4][4];   // [mtile][kstep]
        #pragma unroll
        for (int mt = 0; mt < 4; ++mt) {
            int m = w * 64 + mt * 16 + (l & 15);
            #pragma unroll
            for (int ks = 0; ks < 4; ++ks) {
                int k = ks * 32 + (l >> 4) * 8;
                afrag[mt][ks] = *(const bf16x8*)(cwb + m * 128 + k);
            }
        }
        __syncthreads();

        f32x4 acc[4][4] = {};
        #pragma unroll
        for (int ks = 0; ks < 4; ++ks) {
            bf16x8 bfrag[4];
            #pragma unroll
            for (int nt = 0; nt < 4; ++nt) {
                int row = nt * 16 + (l & 15);
                int colbyte = (ks * 64 + (l >> 4) * 16) ^ ((row & 7) << 4);
                bfrag[nt] = *(const bf16x8*)(xoffT + row * 256 + colbyte);
            }
            #pragma unroll
            for (int mt = 0; mt < 4; ++mt)
                #pragma unroll
                for (int nt = 0; nt < 4; ++nt)
                    acc[mt][nt] = __builtin_amdgcn_mfma_f32_16x16x32_bf16(
                        afrag[mt][ks], bfrag[nt], acc[mt][nt], 0, 0, 0);
        }

        float* ssum = saux;
        float* ssq  = saux + 256;
        #pragma unroll
        for (int mt = 0; mt < 4; ++mt) {
            #pragma unroll
            for (int r = 0; r < 4; ++r) {
                float s = 0.f, qq = 0.f;
                #pragma unroll
                for (int nt = 0; nt < 4; ++nt) {
                    float v = acc[mt][nt][r];
                    s  += v;
                    qq += v * v;
                }
                #pragma unroll
                for (int d = 1; d < 16; d <<= 1) {
                    s  += __shfl_xor(s, d, 64);
                    qq += __shfl_xor(qq, d, 64);
                }
                if ((l & 15) == 0) {
                    int row = w * 64 + mt * 16 + (l >> 4) * 4 + r;
                    ssum[row] = s;
                    ssq[row]  = qq;
                }
            }
        }
        __syncthreads();
        float* gs = gstat + (bidx & 63) * 512;   // 64-way replicated
        atomicAdd(gs + tid,       ssum[tid]);
        atomicAdd(gs + 256 + tid, ssq[tid]);
    }
}

// ---------------- K3: reduce stats -> scale, shift ----------------
__global__ void k_stats(const float* __restrict__ gstat,
                        const float* __restrict__ gamma,
                        const float* __restrict__ beta,
                        float* __restrict__ scaleb, float* __restrict__ shiftb) {
    int t = threadIdx.x;
    float s = 0.f, q = 0.f;
    for (int r = 0; r < 64; ++r) {
        s += gstat[r * 512 + t];
        q += gstat[r * 512 + 256 + t];
    }
    float mean = s / NTOTF;
    float var  = q / NTOTF - mean * mean;
    float rstd = rsqrtf(var + 1e-5f);
    float sc = rstd * gamma[t];
    scaleb[t] = sc;
    shiftb[t] = beta[t] - mean * sc;
}

// ---------------- host ----------------
extern "C" void kernel_launch(void* const* d_in, const int* in_sizes, int n_in,
                              void* d_out, int out_size, void* d_ws, size_t ws_size,
                              hipStream_t stream) {
    (void)in_sizes; (void)n_in; (void)out_size; (void)ws_size;
    const float* x     = (const float*)d_in[0];
    const float* pw    = (const float*)d_in[1];
    const float* pb    = (const float*)d_in[2];
    const float* cw    = (const float*)d_in[3];
    const float* gamma = (const float*)d_in[4];
    const float* beta  = (const float*)d_in[5];
    float* out = (float*)d_out;

    char* ws = (char*)d_ws;
    __bf16* xTb   = (__bf16*)(ws);                     // 8,388,608
    int4*   sidx  = (int4*)(ws + 8388608);             // 4,718,592
    float4* swt   = (float4*)(ws + 13107200);          // 4,718,592
    __bf16* cwb   = (__bf16*)(ws + 17825792);          // 65,536
    float*  gstat = (float*)(ws + 17891328);           // 131,072
    float*  scaleb= (float*)(ws + 18022400);           // 1,024
    float*  shiftb= (float*)(ws + 18023424);           // 1,024

    hipMemsetAsync(gstat, 0, 64 * 512 * 4, stream);
    k_cvt_cw<<<128, 256, 0, stream>>>(cw, cwb);
    k_transpose<<<512, 256, 0, stream>>>(x, xTb);
    k_prep<<<9 * 128, 256, 0, stream>>>(x, pw, pb, sidx, swt);
    k_gemm<false><<<4608, 256, 0, stream>>>(xTb, cwb, sidx, swt,
                                            nullptr, nullptr, gstat, nullptr);
    k_stats<<<1, 256, 0, stream>>>(gstat, gamma, beta, scaleb, shiftb);
    k_gemm<true><<<4608, 256, 0, stream>>>(xTb, cwb, sidx, swt,
                                           scaleb, shiftb, gstat, out);
}